// Round 5
// baseline (24.642 us; speedup 1.0000x reference)
//
#include <hip/hip_runtime.h>
#include <hip/hip_bf16.h>

#define NB  2048
#define BPB 4   // batches per block; grid = NB/BPB = 512 -> 2 blocks/CU

typedef __attribute__((ext_vector_type(8))) short bf16x8;
typedef __attribute__((ext_vector_type(4))) float f32x4;

__device__ __forceinline__ float qget(const float4& q, int c) {
    return c == 0 ? q.x : c == 1 ? q.y : c == 2 ? q.z : q.w;
}
// k is compile-time after #pragma unroll -> static indexing, stays in VGPRs
__device__ __forceinline__ float tget(const float4* T, int k) {
    return qget(T[k >> 2], k & 3);
}

// Block handles batches [b0, b0+BPB). Thread t owns Gamma row (ku,iu) = G[b,ku,iu,:].
// Roll reuse: prev tile == last iter's cur tile (registers). Per batch:
//   stage cur->LDS(bf16), barA, {GJ inverse | split-K 16x16x256 MFMA | Tc}, barB,
//   epilogue (pipelined into next iter): per-thread dots with Minv row -> block sum.
__global__ __launch_bounds__(256, 2)
void curvature_kernel(const float* __restrict__ metric,
                      const float* __restrict__ gamma,
                      float* __restrict__ out)
{
    const int t   = threadIdx.x;
    const int wv  = t >> 6, lane = t & 63;
    const int ku  = t >> 4, iu   = t & 15;
    const int r16 = lane & 15, hi = lane >> 4;
    const int b0  = blockIdx.x * BPB;

    __shared__ alignas(16) unsigned short XA[16][264];  // XA[i][m*16+k] = G[m,i,k]
    __shared__ alignas(16) unsigned short YT[16][264];  // YT[j][m*16+k] = G[k,m,j]
    __shared__ alignas(16) float P[3][16][17];          // split-K term4 partials (waves 1..3)
    __shared__ alignas(16) float MINV[16][20];
    __shared__ alignas(16) float TT[16][20];            // TT[m][k] = G[k,m,k]
    __shared__ float red[4];

    const unsigned roff = t << 4;

    float4 A[4], B[4];            // register tile double-buffer (16 f32 each)
    float4 mr0 = {0,0,0,0}, mr1 = {0,0,0,0};
    float  d[16];
    float  dt = 0.f, tcv = 0.f;

    // ---------------- prologue: A <- tile(b0-1), B <- tile(b0) ----------------
    {
        const float4* pa = (const float4*)(gamma + (((size_t)((b0 + NB - 1) & (NB - 1))) << 12) + roff);
        const float4* pb = (const float4*)(gamma + (((size_t)b0) << 12) + roff);
        A[0]=pa[0]; A[1]=pa[1]; A[2]=pa[2]; A[3]=pa[3];
        B[0]=pb[0]; B[1]=pb[1]; B[2]=pb[2]; B[3]=pb[3];
        if (wv == 0) mr0 = ((const float4*)(metric + ((size_t)b0 << 8)))[lane];
    }

    auto STAGE = [&](const float4* CUR) {
        unsigned yp[8];
        #pragma unroll
        for (int q = 0; q < 8; ++q) {
            union { __hip_bfloat162 h; unsigned u; } cv;
            cv.h = __float22bfloat162_rn(make_float2(tget(CUR, 2*q), tget(CUR, 2*q+1)));
            yp[q] = cv.u;
        }
        uint4* xd = (uint4*)&XA[iu][ku << 4];
        xd[0] = make_uint4(yp[0], yp[1], yp[2], yp[3]);
        xd[1] = make_uint4(yp[4], yp[5], yp[6], yp[7]);
        #pragma unroll
        for (int q = 0; q < 8; ++q) {                   // transposed scatter
            YT[2*q  ][(iu << 4) + ku] = (unsigned short)(yp[q] & 0xffffu);
            YT[2*q+1][(iu << 4) + ku] = (unsigned short)(yp[q] >> 16);
        }
        float cku = tget(CUR, 0);                       // c[ku] via cndmask chain
        #pragma unroll
        for (int k = 1; k < 16; ++k) cku = (ku == k) ? tget(CUR, k) : cku;
        TT[iu][ku] = cku;
    };

    auto COMPUTE = [&](const float4& mcur) {
        if (wv == 0) {
            // shuffle-only Gauss-Jordan inverse (SPD, eig>=1: no pivoting)
            const int gi = lane >> 2, gq = lane & 3;
            float a0 = mcur.x, a1 = mcur.y, a2 = mcur.z, a3 = mcur.w;
            #pragma unroll
            for (int k = 0; k < 16; ++k) {
                const int kq = k >> 2, kc = k & 3;
                float akc = (kc == 0) ? a0 : (kc == 1) ? a1 : (kc == 2) ? a2 : a3;
                float pv = __shfl(akc, (k << 2) | kq);
                float f  = __shfl(akc, (lane & 60) | kq);
                float q0 = __shfl(a0, (k << 2) | gq);
                float q1 = __shfl(a1, (k << 2) | gq);
                float q2 = __shfl(a2, (k << 2) | gq);
                float q3 = __shfl(a3, (k << 2) | gq);
                float pinv = 1.0f / pv;
                bool piv = (gi == k);
                float r0 = q0*pinv, r1 = q1*pinv, r2 = q2*pinv, r3 = q3*pinv;
                a0 = piv ? r0 : fmaf(-f, r0, a0);
                a1 = piv ? r1 : fmaf(-f, r1, a1);
                a2 = piv ? r2 : fmaf(-f, r2, a2);
                a3 = piv ? r3 : fmaf(-f, r3, a3);
                if (gq == kq) {
                    float colv = piv ? pinv : -f * pinv;
                    if      (kc == 0) a0 = colv;
                    else if (kc == 1) a1 = colv;
                    else if (kc == 2) a2 = colv;
                    else              a3 = colv;
                }
            }
            MINV[gi][4*gq + 0] = a0;
            MINV[gi][4*gq + 1] = a1;
            MINV[gi][4*gq + 2] = a2;
            MINV[gi][4*gq + 3] = a3;
        } else {
            // split-K MFMA: wave1 steps 0-2, wave2 steps 3-5, wave3 steps 6-7
            f32x4 acc = {0.f, 0.f, 0.f, 0.f};
            const int sbase = (wv - 1) * 3;
            const int scnt  = (wv == 3) ? 2 : 3;
            #pragma unroll
            for (int s = 0; s < 3; ++s) {
                if (s < scnt) {
                    const int off = ((sbase + s) << 5) + (hi << 3);
                    bf16x8 av = *(const bf16x8*)&XA[r16][off];
                    bf16x8 bv = *(const bf16x8*)&YT[r16][off];
                    acc = __builtin_amdgcn_mfma_f32_16x16x32_bf16(av, bv, acc, 0, 0, 0);
                }
            }
            #pragma unroll
            for (int q = 0; q < 4; ++q)
                P[wv-1][(hi << 2) + q][r16] = acc[q];   // D: col=lane&15, row=4*hi+q
        }
        // Tc[ku]: row-sum of TT (same-ku lanes read same addr -> broadcast)
        const float4* tr = (const float4*)&TT[ku][0];
        float4 s0 = tr[0], s1 = tr[1], s2 = tr[2], s3 = tr[3];
        tcv = ((s0.x + s0.y) + (s0.z + s0.w)) + ((s1.x + s1.y) + (s1.z + s1.w))
            + ((s2.x + s2.y) + (s2.z + s2.w)) + ((s3.x + s3.y) + (s3.z + s3.w));
    };

    // epilogue for the batch whose tile is PRVT (uses d, dt, tcv, P, MINV of that batch)
    auto EPI = [&](const float4* PRVT) {
        const float4* mv = (const float4*)&MINV[iu][0];
        float4 m0 = mv[0], m1 = mv[1], m2 = mv[2], m3 = mv[3];
        float mr[16] = {m0.x,m0.y,m0.z,m0.w, m1.x,m1.y,m1.z,m1.w,
                        m2.x,m2.y,m2.z,m2.w, m3.x,m3.y,m3.z,m3.w};
        float s1 = 0.f, qd = 0.f, R = 0.f;
        #pragma unroll
        for (int k = 0; k < 16; ++k) {
            s1 = fmaf(d[k], mr[k], s1);            // <dA, Minv> partial
            qd = fmaf(tget(PRVT, k), mr[k], qd);   // Q[ku] partial
            R += mr[k];                            // R[iu]
        }
        float mku = mr[0];
        #pragma unroll
        for (int k = 1; k < 16; ++k) mku = (ku == k) ? mr[k] : mku;
        float s4 = (P[0][ku][iu] + P[1][ku][iu] + P[2][ku][iu]) * mku;
        float s = s1 - dt * R + tcv * qd - s4;
        #pragma unroll
        for (int w2 = 1; w2 < 64; w2 <<= 1)
            s += __shfl_xor(s, w2);
        if (lane == 0) red[wv] = s;
    };

    auto ITER = [&](int bi, float4* PRV, float4* CUR, const float4& mcur, float4& mnxt,
                    bool first, bool issueNext) {
        if (!first) EPI(PRV);                      // finalize batch bi-1 (reads P/MINV pre-barA)
        #pragma unroll
        for (int k = 0; k < 16; ++k) d[k] = tget(PRV, k) - tget(CUR, k);  // prev - cur
        dt = d[0];
        #pragma unroll
        for (int k = 1; k < 16; ++k) dt = (ku == k) ? d[k] : dt;
        if (issueNext) {                           // prefetch tile(bi+1) into freed PRV regs
            const float4* pn = (const float4*)(gamma + (((size_t)(bi + 1)) << 12) + roff);
            PRV[0] = pn[0]; PRV[1] = pn[1]; PRV[2] = pn[2]; PRV[3] = pn[3];
            if (wv == 0) mnxt = ((const float4*)(metric + ((size_t)(bi + 1) << 8)))[lane];
        }
        STAGE(CUR);
        __syncthreads();                           // barA: staging visible; prior red final
        if (!first && t == 0)
            out[bi - 1] = (red[0] + red[1]) + (red[2] + red[3]);
        COMPUTE(mcur);
        __syncthreads();                           // barB: P/MINV/tcv ready for epilogue
    };

    ITER(b0 + 0, A, B, mr0, mr1, true,  true);
    ITER(b0 + 1, B, A, mr1, mr0, false, true);
    ITER(b0 + 2, A, B, mr0, mr1, false, true);
    ITER(b0 + 3, B, A, mr1, mr0, false, false);

    // drain: finalize batch b0+3 (its tile is in A)
    EPI(A);
    __syncthreads();
    if (t == 0) out[b0 + 3] = (red[0] + red[1]) + (red[2] + red[3]);
}

extern "C" void kernel_launch(void* const* d_in, const int* in_sizes, int n_in,
                              void* d_out, int out_size, void* d_ws, size_t ws_size,
                              hipStream_t stream) {
    const float* metric = (const float*)d_in[0];   // (2048, 16, 16) f32
    const float* gamma  = (const float*)d_in[1];   // (2048, 16, 16, 16) f32
    float* out = (float*)d_out;                    // (2048,) f32
    curvature_kernel<<<NB / BPB, 256, 0, stream>>>(metric, gamma, out);
}

// Round 7
// 15.928 us; speedup vs baseline: 1.5471x; 1.5471x over previous
//
#include <hip/hip_runtime.h>
#include <hip/hip_bf16.h>

#define NB 2048

typedef __attribute__((ext_vector_type(8))) short bf16x8;
typedef __attribute__((ext_vector_type(4))) float f32x4;

__device__ __forceinline__ float qget(const float4& q, int c) {
    return c == 0 ? q.x : c == 1 ? q.y : c == 2 ? q.z : q.w;
}

// One block per batch (2048 blocks). Thread t owns Gamma row (ku,iu)=G[b,ku,iu,:].
// scalar[b] = <Aprev-Acur,Minv> - sum_i dT[i]*R[i] + sum_m T[m]*Q[m] - <term4,Minv>
// term4 = 16x16x256 bf16 MFMA: A[i][l]=G[m,i,k], B[l][j]=G[k,m,j], l=m*16+k.
//   XA row-major (contiguous writes); YT[j][l]=B[l][j] via b16 scatter (proven r4).
// GJ wave (b&3): shuffle-only 16x16 SPD inverse. Other 3 waves split K 3/3/2 and
// contract their term4 partial with Minv locally (no P buffer).
__global__ __launch_bounds__(256, 4)
void curvature_kernel(const float* __restrict__ metric,
                      const float* __restrict__ gamma,
                      float* __restrict__ out)
{
    const int bid = blockIdx.x;
    const int b = ((bid & 7) << 8) | (bid >> 3);   // XCD swizzle: b, b-1 share an L2
    const int t = threadIdx.x;
    const int wv = t >> 6, lane = t & 63;
    const int ku = t >> 4, iu = t & 15;
    const int r16 = lane & 15, hi = lane >> 4;
    const int gjw = b & 3;                          // GJ wave id: spread across SIMDs

    __shared__ alignas(16) unsigned short XA[16][264];  // XA[i][m*16+k] = G[m,i,k]
    __shared__ alignas(16) unsigned short YT[16][264];  // YT[j][m*16+k] = G[k,m,j]
    __shared__ alignas(16) float MINV[16][20];
    __shared__ alignas(16) float TT[16][20];             // TT[m][k] = G[k,m,k]
    __shared__ float red[4];

    const float* Gc = gamma + ((size_t)b << 12);
    const float* Gp = gamma + ((size_t)((b + NB - 1) & (NB - 1)) << 12);

    // ---- all global loads up front (independent) ----
    const float4* gc4 = (const float4*)(Gc + (t << 4));
    const float4* gp4 = (const float4*)(Gp + (t << 4));
    float4 g0 = gc4[0], g1 = gc4[1], g2 = gc4[2], g3 = gc4[3];
    float4 p0 = gp4[0], p1 = gp4[1], p2 = gp4[2], p3 = gp4[3];
    float gku = Gc[(t << 4) + ku];     // G[b,  ku, iu, ku]  (L1 hit)
    float pku = Gp[(t << 4) + ku];     // G[b-1,ku, iu, ku]
    float4 mrow = {0.f, 0.f, 0.f, 0.f};
    if (wv == gjw) mrow = ((const float4*)(metric + ((size_t)b << 8)))[lane];

    // ---- pack row to bf16 (8 packed words) ----
    unsigned yp[8];
    {
        float4 gq[4] = {g0, g1, g2, g3};
        #pragma unroll
        for (int q = 0; q < 8; ++q) {
            union { __hip_bfloat162 h; unsigned u; } cv;
            cv.h = __float22bfloat162_rn(
                make_float2(qget(gq[q >> 1], (q & 1) * 2),
                            qget(gq[q >> 1], (q & 1) * 2 + 1)));
            yp[q] = cv.u;
        }
    }
    // A: XA[iu][ku*16 + 0..15] — contiguous (l = m*16+k with m=ku, k=j)
    {
        uint4* xd = (uint4*)&XA[iu][ku << 4];
        xd[0] = make_uint4(yp[0], yp[1], yp[2], yp[3]);
        xd[1] = make_uint4(yp[4], yp[5], yp[6], yp[7]);
    }
    // B^T: YT[j][iu*16+ku] = G[ku,iu,j] — transposed b16 scatter (proven round 4)
    #pragma unroll
    for (int q = 0; q < 8; ++q) {
        YT[2*q  ][(iu << 4) + ku] = (unsigned short)(yp[q] & 0xffffu);
        YT[2*q+1][(iu << 4) + ku] = (unsigned short)(yp[q] >> 16);
    }
    TT[iu][ku] = gku;
    __syncthreads();   // barA: XA, YT, TT visible

    // ---- compute phase ----
    f32x4 acc = {0.f, 0.f, 0.f, 0.f};
    const bool isGJ = (wv == gjw);
    if (isGJ) {
        // shuffle-only Gauss-Jordan inverse (SPD, eig>=1: no pivoting)
        const int gi = lane >> 2, gq2 = lane & 3;
        float a0 = mrow.x, a1 = mrow.y, a2 = mrow.z, a3 = mrow.w;
        #pragma unroll
        for (int k = 0; k < 16; ++k) {
            const int kq = k >> 2, kc = k & 3;
            float akc = (kc == 0) ? a0 : (kc == 1) ? a1 : (kc == 2) ? a2 : a3;
            float pv = __shfl(akc, (k << 2) | kq);
            float f  = __shfl(akc, (lane & 60) | kq);
            float q0 = __shfl(a0, (k << 2) | gq2);
            float q1 = __shfl(a1, (k << 2) | gq2);
            float q2 = __shfl(a2, (k << 2) | gq2);
            float q3 = __shfl(a3, (k << 2) | gq2);
            float pinv = 1.0f / pv;
            bool piv = (gi == k);
            float r0 = q0*pinv, r1 = q1*pinv, r2 = q2*pinv, r3 = q3*pinv;
            a0 = piv ? r0 : fmaf(-f, r0, a0);
            a1 = piv ? r1 : fmaf(-f, r1, a1);
            a2 = piv ? r2 : fmaf(-f, r2, a2);
            a3 = piv ? r3 : fmaf(-f, r3, a3);
            if (gq2 == kq) {
                float colv = piv ? pinv : -f * pinv;
                if      (kc == 0) a0 = colv;
                else if (kc == 1) a1 = colv;
                else if (kc == 2) a2 = colv;
                else              a3 = colv;
            }
        }
        MINV[gi][4*gq2 + 0] = a0;
        MINV[gi][4*gq2 + 1] = a1;
        MINV[gi][4*gq2 + 2] = a2;
        MINV[gi][4*gq2 + 3] = a3;
    } else {
        // split-K MFMA: mw = 0,1,2 -> K-steps {0-2},{3-5},{6-7}
        const int mw = (wv - gjw + 3) & 3;
        const int sbase = mw * 3;
        const int scnt  = (mw == 2) ? 2 : 3;
        #pragma unroll
        for (int s = 0; s < 3; ++s) {
            if (s < scnt) {
                const int off = ((sbase + s) << 5) + (hi << 3);
                bf16x8 av = *(const bf16x8*)&XA[r16][off];
                bf16x8 bv = *(const bf16x8*)&YT[r16][off];
                acc = __builtin_amdgcn_mfma_f32_16x16x32_bf16(av, bv, acc, 0, 0, 0);
            }
        }
    }
    __syncthreads();   // barB: MINV ready; accs live in registers

    // ---- epilogue: per-thread dots with Minv ----
    float mr[16];
    {
        const float4* mv = (const float4*)&MINV[iu][0];
        float4 m0 = mv[0], m1 = mv[1], m2 = mv[2], m3 = mv[3];
        mr[0]=m0.x; mr[1]=m0.y; mr[2]=m0.z; mr[3]=m0.w;
        mr[4]=m1.x; mr[5]=m1.y; mr[6]=m1.z; mr[7]=m1.w;
        mr[8]=m2.x; mr[9]=m2.y; mr[10]=m2.z; mr[11]=m2.w;
        mr[12]=m3.x; mr[13]=m3.y; mr[14]=m3.z; mr[15]=m3.w;
    }
    // tcv = T[ku] = sum_k TT[ku][k]  (broadcast reads: same-ku lanes same addr)
    float tcv;
    {
        const float4* tr = (const float4*)&TT[ku][0];
        float4 s0 = tr[0], s1 = tr[1], s2 = tr[2], s3 = tr[3];
        tcv = ((s0.x+s0.y)+(s0.z+s0.w)) + ((s1.x+s1.y)+(s1.z+s1.w))
            + ((s2.x+s2.y)+(s2.z+s2.w)) + ((s3.x+s3.y)+(s3.z+s3.w));
    }
    float pd = 0.f, qd = 0.f, R = 0.f;
    {
        float4 gq[4] = {g0, g1, g2, g3};
        float4 pq[4] = {p0, p1, p2, p3};
        #pragma unroll
        for (int k = 0; k < 16; ++k) {
            float m = mr[k];
            pd = fmaf(qget(pq[k >> 2], k & 3), m, pd);   // <Gprev row, Minv row>
            qd = fmaf(qget(gq[k >> 2], k & 3), m, qd);   // <Gcur row,  Minv row>
            R += m;                                       // R[iu]
        }
    }
    float dt = pku - gku;
    float s = fmaf(tcv - 1.0f, qd, pd) - dt * R;   // (pd-qd) + tcv*qd - dt*R
    if (!isGJ) {
        // local term4 contraction: D row = 4*hi+q, col = r16
        float t4c = acc[0] * MINV[(hi << 2) + 0][r16]
                  + acc[1] * MINV[(hi << 2) + 1][r16]
                  + acc[2] * MINV[(hi << 2) + 2][r16]
                  + acc[3] * MINV[(hi << 2) + 3][r16];
        s -= t4c;
    }
    #pragma unroll
    for (int w2 = 1; w2 < 64; w2 <<= 1)
        s += __shfl_xor(s, w2);
    if (lane == 0) red[wv] = s;
    __syncthreads();
    if (t == 0) out[b] = (red[0] + red[1]) + (red[2] + red[3]);
}

extern "C" void kernel_launch(void* const* d_in, const int* in_sizes, int n_in,
                              void* d_out, int out_size, void* d_ws, size_t ws_size,
                              hipStream_t stream) {
    const float* metric = (const float*)d_in[0];   // (2048, 16, 16) f32
    const float* gamma  = (const float*)d_in[1];   // (2048, 16, 16, 16) f32
    float* out = (float*)d_out;                    // (2048,) f32
    curvature_kernel<<<NB, 256, 0, stream>>>(metric, gamma, out);
}

// Round 8
// 15.873 us; speedup vs baseline: 1.5525x; 1.0035x over previous
//
#include <hip/hip_runtime.h>
#include <hip/hip_bf16.h>

#define NB 2048

typedef __attribute__((ext_vector_type(8))) short bf16x8;
typedef __attribute__((ext_vector_type(4))) float f32x4;

__device__ __forceinline__ float qget(const float4& q, int c) {
    return c == 0 ? q.x : c == 1 ? q.y : c == 2 ? q.z : q.w;
}

// One block per batch (2048 blocks). Thread t owns Gamma row (ku,iu)=G[b,ku,iu,:].
// scalar[b] = <Aprev-Acur,Minv> - sum_i dT[i]*R[i] + sum_m T[m]*Q[m] - <term4,Minv>
// term4 = 16x16x256 bf16 MFMA: A[i][l]=G[m,i,k], B[l][j]=G[k,m,j], l=m*16+k.
// Schedule (2 barriers): GJ inverse runs BEFORE barA (depends only on mrow,
// overlaps gamma-load latency + staging). After barA: all 4 waves take 2 K-steps
// of the MFMA each, then contract locally with Minv; one final barrier for out.
__global__ __launch_bounds__(256, 4)
void curvature_kernel(const float* __restrict__ metric,
                      const float* __restrict__ gamma,
                      float* __restrict__ out)
{
    const int bid = blockIdx.x;
    const int b = ((bid & 7) << 8) | (bid >> 3);   // XCD swizzle: b, b-1 share an L2
    const int t = threadIdx.x;
    const int wv = t >> 6, lane = t & 63;
    const int ku = t >> 4, iu = t & 15;
    const int r16 = lane & 15, hi = lane >> 4;
    const int gjw = b & 3;                          // GJ wave id: spread across SIMDs

    __shared__ alignas(16) unsigned short XA[16][264];  // XA[i][m*16+k] = G[m,i,k]
    __shared__ alignas(16) unsigned short YT[16][264];  // YT[j][m*16+k] = G[k,m,j]
    __shared__ alignas(16) float MINV[16][20];
    __shared__ alignas(16) float TT[16][20];             // TT[m][k] = G[k,m,k]
    __shared__ float red[4];

    const float* Gc = gamma + ((size_t)b << 12);
    const float* Gp = gamma + ((size_t)((b + NB - 1) & (NB - 1)) << 12);

    // ---- all global loads up front (independent) ----
    const float4* gc4 = (const float4*)(Gc + (t << 4));
    const float4* gp4 = (const float4*)(Gp + (t << 4));
    float4 g0 = gc4[0], g1 = gc4[1], g2 = gc4[2], g3 = gc4[3];
    float4 p0 = gp4[0], p1 = gp4[1], p2 = gp4[2], p3 = gp4[3];
    float gku = Gc[(t << 4) + ku];     // G[b,  ku, iu, ku]  (L1 hit)
    float pku = Gp[(t << 4) + ku];     // G[b-1,ku, iu, ku]
    float4 mrow = {0.f, 0.f, 0.f, 0.f};
    const bool isGJ = (wv == gjw);
    if (isGJ) mrow = ((const float4*)(metric + ((size_t)b << 8)))[lane];

    // ---- GJ wave: shuffle-only Gauss-Jordan inverse, BEFORE barA ----
    // Depends only on mrow; runs while gamma loads are in flight and other
    // waves stage. MINV is visible to everyone at barA.
    if (isGJ) {
        const int gi = lane >> 2, gq2 = lane & 3;
        float a0 = mrow.x, a1 = mrow.y, a2 = mrow.z, a3 = mrow.w;
        #pragma unroll
        for (int k = 0; k < 16; ++k) {
            const int kq = k >> 2, kc = k & 3;
            float akc = (kc == 0) ? a0 : (kc == 1) ? a1 : (kc == 2) ? a2 : a3;
            float pv = __shfl(akc, (k << 2) | kq);
            float f  = __shfl(akc, (lane & 60) | kq);
            float q0 = __shfl(a0, (k << 2) | gq2);
            float q1 = __shfl(a1, (k << 2) | gq2);
            float q2 = __shfl(a2, (k << 2) | gq2);
            float q3 = __shfl(a3, (k << 2) | gq2);
            float pinv = 1.0f / pv;
            bool piv = (gi == k);
            float r0 = q0*pinv, r1 = q1*pinv, r2 = q2*pinv, r3 = q3*pinv;
            a0 = piv ? r0 : fmaf(-f, r0, a0);
            a1 = piv ? r1 : fmaf(-f, r1, a1);
            a2 = piv ? r2 : fmaf(-f, r2, a2);
            a3 = piv ? r3 : fmaf(-f, r3, a3);
            if (gq2 == kq) {
                float colv = piv ? pinv : -f * pinv;
                if      (kc == 0) a0 = colv;
                else if (kc == 1) a1 = colv;
                else if (kc == 2) a2 = colv;
                else              a3 = colv;
            }
        }
        MINV[gi][4*gq2 + 0] = a0;
        MINV[gi][4*gq2 + 1] = a1;
        MINV[gi][4*gq2 + 2] = a2;
        MINV[gi][4*gq2 + 3] = a3;
    }

    // ---- pack row to bf16 + stage (all waves) ----
    unsigned yp[8];
    {
        float4 gq[4] = {g0, g1, g2, g3};
        #pragma unroll
        for (int q = 0; q < 8; ++q) {
            union { __hip_bfloat162 h; unsigned u; } cv;
            cv.h = __float22bfloat162_rn(
                make_float2(qget(gq[q >> 1], (q & 1) * 2),
                            qget(gq[q >> 1], (q & 1) * 2 + 1)));
            yp[q] = cv.u;
        }
    }
    {   // A: XA[iu][ku*16 + 0..15] — contiguous
        uint4* xd = (uint4*)&XA[iu][ku << 4];
        xd[0] = make_uint4(yp[0], yp[1], yp[2], yp[3]);
        xd[1] = make_uint4(yp[4], yp[5], yp[6], yp[7]);
    }
    #pragma unroll
    for (int q = 0; q < 8; ++q) {   // B^T: YT[j][iu*16+ku] — b16 scatter
        YT[2*q  ][(iu << 4) + ku] = (unsigned short)(yp[q] & 0xffffu);
        YT[2*q+1][(iu << 4) + ku] = (unsigned short)(yp[q] >> 16);
    }
    TT[iu][ku] = gku;
    __syncthreads();   // barA: XA, YT, TT, MINV all visible

    // ---- every wave: 2 K-steps of the 16x16x256 MFMA ----
    f32x4 acc = {0.f, 0.f, 0.f, 0.f};
    #pragma unroll
    for (int s = 0; s < 2; ++s) {
        const int off = ((2 * wv + s) << 5) + (hi << 3);
        bf16x8 av = *(const bf16x8*)&XA[r16][off];
        bf16x8 bv = *(const bf16x8*)&YT[r16][off];
        acc = __builtin_amdgcn_mfma_f32_16x16x32_bf16(av, bv, acc, 0, 0, 0);
    }

    // ---- epilogue: per-thread dots with Minv ----
    float mr[16];
    {
        const float4* mv = (const float4*)&MINV[iu][0];
        float4 m0 = mv[0], m1 = mv[1], m2 = mv[2], m3 = mv[3];
        mr[0]=m0.x; mr[1]=m0.y; mr[2]=m0.z; mr[3]=m0.w;
        mr[4]=m1.x; mr[5]=m1.y; mr[6]=m1.z; mr[7]=m1.w;
        mr[8]=m2.x; mr[9]=m2.y; mr[10]=m2.z; mr[11]=m2.w;
        mr[12]=m3.x; mr[13]=m3.y; mr[14]=m3.z; mr[15]=m3.w;
    }
    // tcv = T[ku] = sum_k TT[ku][k]  (broadcast reads: same-ku lanes same addr)
    float tcv;
    {
        const float4* tr = (const float4*)&TT[ku][0];
        float4 s0 = tr[0], s1 = tr[1], s2 = tr[2], s3 = tr[3];
        tcv = ((s0.x+s0.y)+(s0.z+s0.w)) + ((s1.x+s1.y)+(s1.z+s1.w))
            + ((s2.x+s2.y)+(s2.z+s2.w)) + ((s3.x+s3.y)+(s3.z+s3.w));
    }
    float pd = 0.f, qd = 0.f, R = 0.f;
    {
        float4 gq[4] = {g0, g1, g2, g3};
        float4 pq[4] = {p0, p1, p2, p3};
        #pragma unroll
        for (int k = 0; k < 16; ++k) {
            float m = mr[k];
            pd = fmaf(qget(pq[k >> 2], k & 3), m, pd);   // <Gprev row, Minv row>
            qd = fmaf(qget(gq[k >> 2], k & 3), m, qd);   // <Gcur row,  Minv row>
            R += m;                                       // R[iu]
        }
    }
    float dt = pku - gku;
    // local term4 contraction: D row = 4*hi+q, col = r16
    float t4c = acc[0] * MINV[(hi << 2) + 0][r16]
              + acc[1] * MINV[(hi << 2) + 1][r16]
              + acc[2] * MINV[(hi << 2) + 2][r16]
              + acc[3] * MINV[(hi << 2) + 3][r16];
    float s = fmaf(tcv - 1.0f, qd, pd) - dt * R - t4c;  // (pd-qd)+tcv*qd-dt*R-t4c

    #pragma unroll
    for (int w2 = 1; w2 < 64; w2 <<= 1)
        s += __shfl_xor(s, w2);
    if (lane == 0) red[wv] = s;
    __syncthreads();
    if (t == 0) out[b] = (red[0] + red[1]) + (red[2] + red[3]);
}

extern "C" void kernel_launch(void* const* d_in, const int* in_sizes, int n_in,
                              void* d_out, int out_size, void* d_ws, size_t ws_size,
                              hipStream_t stream) {
    const float* metric = (const float*)d_in[0];   // (2048, 16, 16) f32
    const float* gamma  = (const float*)d_in[1];   // (2048, 16, 16, 16) f32
    float* out = (float*)d_out;                    // (2048,) f32
    curvature_kernel<<<NB, 256, 0, stream>>>(metric, gamma, out);
}